// Round 9
// baseline (4707.475 us; speedup 1.0000x reference)
//
#include <hip/hip_runtime.h>
#include <hip/hip_bf16.h>

#define T_  512
#define FS_ 64
#define FC_ 32
#define H_  256
#define APAD 272

// ws layout (bf16 element offsets)
#define WS_REC0 0        // [32 ft][8 ks][64 lane][8]   even ft = Wg_h, odd = Wrec
#define WS_REC1 131072
#define WS_X1P  262144   // [32][8][64][8]              even ft = Win1, odd = Wg_x1
#define WS_X0S  393216   // [32][2][64][8]              even ft = Win0, odd = Wg_x0
#define WS_X0C  425984   // [32][1][64][8]
#define WS_MBOX 458752   // [32 tiles][2 parity][16*256] bf16 h0 mailbox
#define WS_FLAG_BYTE ((458752 + 262144) * 2)   // 128 ints: pub[64], ack[64]

typedef __attribute__((ext_vector_type(8))) short bfrag;
typedef __attribute__((ext_vector_type(4))) float ffrag;

__device__ __forceinline__ ffrag mfma16(bfrag a, bfrag b, ffrag c) {
    return __builtin_amdgcn_mfma_f32_16x16x32_bf16(a, b, c, 0, 0, 0);
}
__device__ __forceinline__ float fast_tanh(float x) {
    float e = __builtin_amdgcn_exp2f(x * 2.8853901817f);   // exp(2x), inf-safe
    return 1.f - 2.f * __builtin_amdgcn_rcpf(e + 1.f);
}
__device__ __forceinline__ void bar_lds() {
    asm volatile("s_waitcnt lgkmcnt(0)\n\ts_barrier" ::: "memory");
}

// ---------------- prepack: fp32 weights -> bf16 MFMA B-fragments + flag reset ---
__global__ __launch_bounds__(256) void prepack_kernel(
    const float* __restrict__ Win0, const float* __restrict__ Wrec0, const float* __restrict__ Wg0,
    const float* __restrict__ Win1, const float* __restrict__ Wrec1, const float* __restrict__ Wg1,
    __hip_bfloat16* __restrict__ ws)
{
    int g = blockIdx.x * 256 + threadIdx.x;
    if (g < 128) ((int*)((char*)ws + WS_FLAG_BYTE))[g] = 0;   // pub/ack flags: reset every launch
    if (g >= 55296) return;
    int lane = g & 63;
    int frag = g >> 6;
    int lm = lane & 15, qq = lane >> 4;
    const float* src;
    int dstoff;
    if (frag < 256) {
        int f = frag, ft = f >> 3, ks = f & 7;
        int n = (ft >> 1) * 16 + lm, kk = ks * 32 + qq * 8;
        src = (ft & 1) ? (Wrec0 + n * 256 + kk) : (Wg0 + n * 352 + 96 + kk);
        dstoff = WS_REC0 + (f * 64 + lane) * 8;
    } else if (frag < 512) {
        int f = frag - 256, ft = f >> 3, ks = f & 7;
        int n = (ft >> 1) * 16 + lm, kk = ks * 32 + qq * 8;
        src = (ft & 1) ? (Wrec1 + n * 256 + kk) : (Wg1 + n * 512 + 256 + kk);
        dstoff = WS_REC1 + (f * 64 + lane) * 8;
    } else if (frag < 768) {
        int f = frag - 512, ft = f >> 3, ks = f & 7;
        int n = (ft >> 1) * 16 + lm, kk = ks * 32 + qq * 8;
        src = (ft & 1) ? (Wg1 + n * 512 + kk) : (Win1 + n * 256 + kk);
        dstoff = WS_X1P + (f * 64 + lane) * 8;
    } else if (frag < 832) {
        int f = frag - 768, ft = f >> 1, ks = f & 1;
        int n = (ft >> 1) * 16 + lm, kk = ks * 32 + qq * 8;
        src = (ft & 1) ? (Wg0 + n * 352 + kk) : (Win0 + n * 96 + kk);
        dstoff = WS_X0S + (f * 64 + lane) * 8;
    } else {
        int f = frag - 832, ft = f;
        int n = (ft >> 1) * 16 + lm, kk = qq * 8;
        src = (ft & 1) ? (Wg0 + n * 352 + 64 + kk) : (Win0 + n * 96 + 64 + kk);
        dstoff = WS_X0C + (f * 64 + lane) * 8;
    }
    __hip_bfloat16* d = ws + dstoff;
#pragma unroll
    for (int j = 0; j < 8; j++) d[j] = __float2bfloat16(src[j]);
}

// ---------------- main: 64 WGs = 32 layer-0 producers + 32 layer-1 consumers ----
// R3/R8 topology verbatim. The bottleneck (measured R3==R8: 8.7 us/step) is the
// per-deriv L2 restream of the 128-VGPR rec/gate weight set: the allocator's
// occupancy heuristic keeps pressure <=128 (VGPR_Count=128 both rounds) and
// remats the weights from L2 every deriv (256 KB/CU/deriv / ~64 B/cy = ~1.7 us
// x 4 derivs = the whole step). Fix: amdgpu_waves_per_eu(2,2) removes the
// occupancy incentive (max 2 waves/EU -> 256-VGPR budget is free), and per-
// iteration asm pins anchor the weights live. Pins were toxic ONLY under the
// 128 budget (R4/R7 spill storms); at 256, weights(128)+working(~100) fit.
// Grid 64 on 256 CUs -> 1 WG/CU either way; occupancy cost nil.
__global__ __launch_bounds__(512)
__attribute__((amdgpu_waves_per_eu(2, 2))) void lnn_main(
    const float* __restrict__ seq, const float* __restrict__ ctx,
    const float* __restrict__ tau0, const float* __restrict__ bg0,
    const float* __restrict__ lng0, const float* __restrict__ lnb0,
    const float* __restrict__ tau1, const float* __restrict__ bg1,
    const float* __restrict__ lng1, const float* __restrict__ lnb1,
    const float* __restrict__ cW1, const float* __restrict__ cb1,
    const float* __restrict__ cW2, const float* __restrict__ cb2,
    __hip_bfloat16* __restrict__ ws, float* __restrict__ out)
{
    __shared__ __align__(16) float hbuf[16][260];
    __shared__ __align__(16) float hn[16][260];
    __shared__ __align__(16) __hip_bfloat16 abf[2][16][APAD];
    __shared__ __align__(16) __hip_bfloat16 x1A[16][APAD];     // B: staged h0 tile
    __shared__ __align__(16) __hip_bfloat16 xsb[16][80];       // A: ctx/seq staging
    __shared__ __align__(16) float lnw[256], lnb[256];

    const int tid  = threadIdx.x;
    const int wave = tid >> 6, lane = tid & 63;     // 8 waves
    const int qq   = lane >> 4, lm = lane & 15;
    const int bid  = blockIdx.x;
    const int tile = bid & 31, roleB = bid >> 5;
    const int brow = tile * 16;

    int* flags = (int*)((char*)ws + WS_FLAG_BYTE);
    int* pubf  = flags + tile * 2;          // [parity]
    int* ackf  = flags + 64 + tile * 2;     // [parity]
    __hip_bfloat16* mb0 = ws + WS_MBOX + tile * 2 * 4096;

    for (int e = tid; e < 16 * 260; e += 512) ((float*)hbuf)[e] = 0.f;
    for (int e = tid; e < 2 * 16 * APAD; e += 512)
        ((__hip_bfloat16*)abf)[e] = __float2bfloat16(0.f);
    if (tid < 256) {
        const float* lg = roleB ? lng1 : lng0;
        const float* lb = roleB ? lnb1 : lnb0;
        lnw[tid] = lg[tid]; lnb[tid] = lb[tid];
    }
    // per-block (C=2) column params: colb = wave*32 + b*16 + lm
    float rtp[2], bgr[2];
#pragma unroll
    for (int b = 0; b < 2; b++) {
        int colb = wave * 32 + b * 16 + lm;
        float tv = roleB ? tau1[colb] : tau0[colb];
        float sp = fmaxf(tv, 0.f) + logf(1.f + __expf(-fabsf(tv)));
        rtp[b] = 1.f / (sp + 1.f);
        bgr[b] = roleB ? bg1[colb] : bg0[colb];
    }

    // ---- rec/gate weights: 2 col-blocks x 8 ks x (gate,rec) = 128 VGPR.
    // Loaded ONCE; pinned live each iteration (budget 256 via waves_per_eu(2,2)).
    bfrag cg[2][8], cr[2][8];
    {
        const __hip_bfloat16* rp = ws + (roleB ? WS_REC1 : WS_REC0);
#pragma unroll
        for (int b = 0; b < 2; b++) {
            int ct = 2 * wave + b;
#pragma unroll
            for (int ks = 0; ks < 8; ks++) {
                cg[b][ks] = *(const bfrag*)(rp + ((16 * ct + ks) * 64 + lane) * 8);
                cr[b][ks] = *(const bfrag*)(rp + ((16 * ct + 8 + ks) * 64 + lane) * 8);
            }
        }
    }
    auto pinrec = [&]() {
#pragma unroll
        for (int b = 0; b < 2; b++)
#pragma unroll
            for (int ks = 0; ks < 8; ks++) {
                asm volatile("" : "+v"(cg[b][ks]));
                asm volatile("" : "+v"(cr[b][ks]));
            }
    };

    float xwin[2][4], xgate[2][4], hbase[2][4], hh[2][4], ksum[2][4];

    auto deriv = [&](const __hip_bfloat16 (*Ar)[APAD], __hip_bfloat16 (*Aw)[APAD], int d) {
        ffrag ag[2], ar[2];
#pragma unroll
        for (int b = 0; b < 2; b++) {
            ag[b] = (ffrag){0.f, 0.f, 0.f, 0.f};
            ar[b] = (ffrag){0.f, 0.f, 0.f, 0.f};
        }
#pragma unroll
        for (int ks = 0; ks < 8; ks++) {
            bfrag a = *(const bfrag*)&Ar[lm][ks * 32 + qq * 8];   // read ONCE
            ag[0] = mfma16(a, cg[0][ks], ag[0]);
            ar[0] = mfma16(a, cr[0][ks], ar[0]);
            ag[1] = mfma16(a, cg[1][ks], ag[1]);
            ar[1] = mfma16(a, cr[1][ks], ar[1]);
        }
        float wsm = (d == 1 || d == 2) ? 2.f : 1.f;
        float an  = (d < 2) ? 0.5f : 1.f;
#pragma unroll
        for (int b = 0; b < 2; b++) {
            int colb = wave * 32 + b * 16 + lm;
#pragma unroll
            for (int r = 0; r < 4; r++) {
                float t  = fast_tanh(ag[b][r] + xgate[b][r]);
                float t2 = t * t;
                float g  = 0.5f + t * (0.25f + t2 * (-(1.f / 48.f) + t2 * (1.f / 480.f)));
                float kd = xwin[b][r] - hh[b][r] * rtp[b] + g * ar[b][r];
                ksum[b][r] += wsm * kd;
                if (d < 3) {
                    float hhn = hbase[b][r] + an * kd;
                    hh[b][r] = hhn;
                    Aw[qq * 4 + r][colb] = __float2bfloat16(hhn);
                } else {
                    hn[qq * 4 + r][colb] = hbase[b][r] + ksum[b][r] * (1.f / 6.f);
                }
            }
        }
    };
    auto loadbase = [&]() {
#pragma unroll
        for (int b = 0; b < 2; b++) {
            int colb = wave * 32 + b * 16 + lm;
#pragma unroll
            for (int r = 0; r < 4; r++) {
                float v = hbuf[qq * 4 + r][colb];
                hbase[b][r] = v; hh[b][r] = v; ksum[b][r] = 0.f;
            }
        }
    };
    auto lnorm = [&](__hip_bfloat16* mbslot) {
#pragma unroll
        for (int i = 0; i < 2; i++) {                 // 8 waves x 2 rows = 16 rows
            int rr = wave + i * 8, c0 = lane * 4;
            float4 vv = *(const float4*)&hn[rr][c0];
            float v[4] = {vv.x, vv.y, vv.z, vv.w};
            float s  = v[0] + v[1] + v[2] + v[3];
            float s2 = v[0]*v[0] + v[1]*v[1] + v[2]*v[2] + v[3]*v[3];
#pragma unroll
            for (int m = 1; m <= 32; m <<= 1) {
                s  += __shfl_xor(s, m, 64);
                s2 += __shfl_xor(s2, m, 64);
            }
            float mean = s * (1.f / 256.f);
            float var  = s2 * (1.f / 256.f) - mean * mean;
            float rs   = __builtin_amdgcn_rsqf(var + 1e-5f);
            float4 lw = *(const float4*)&lnw[c0];
            float4 lb = *(const float4*)&lnb[c0];
            float hv[4];
            __align__(8) __hip_bfloat16 hb[4];
            hv[0] = fast_tanh((v[0] - mean) * rs * lw.x + lb.x);
            hv[1] = fast_tanh((v[1] - mean) * rs * lw.y + lb.y);
            hv[2] = fast_tanh((v[2] - mean) * rs * lw.z + lb.z);
            hv[3] = fast_tanh((v[3] - mean) * rs * lw.w + lb.w);
#pragma unroll
            for (int j = 0; j < 4; j++) hb[j] = __float2bfloat16(hv[j]);
            *(float4*)&hbuf[rr][c0] = (float4){hv[0], hv[1], hv[2], hv[3]};
            *(uint2*)&abf[0][rr][c0] = *(uint2*)hb;
            if (mbslot)
                __hip_atomic_store((unsigned long long*)&mbslot[rr * 256 + c0],
                                   *(unsigned long long*)hb,
                                   __ATOMIC_RELAXED, __HIP_MEMORY_SCOPE_AGENT);
        }
    };

    if (!roleB) {
        // =================== role A: layer 0 producer ===================
        for (int e = tid; e < 16 * FC_; e += 512) {
            int r = e >> 5, c = e & 31;
            xsb[r][c] = __float2bfloat16(ctx[(brow + r) * FC_ + c]);
        }
        __syncthreads();
        float xcw[2][4], xcg[2][4];
#pragma unroll
        for (int b = 0; b < 2; b++) {
            int ct = 2 * wave + b;
            bfrag a = *(const bfrag*)&xsb[lm][qq * 8];
            ffrag zw = {0.f, 0.f, 0.f, 0.f}, zg = {0.f, 0.f, 0.f, 0.f};
            bfrag bw  = *(const bfrag*)(ws + WS_X0C + ((2 * ct) * 64 + lane) * 8);
            bfrag bgf = *(const bfrag*)(ws + WS_X0C + ((2 * ct + 1) * 64 + lane) * 8);
            zw = mfma16(a, bw, zw);
            zg = mfma16(a, bgf, zg);
#pragma unroll
            for (int r = 0; r < 4; r++) { xcw[b][r] = zw[r]; xcg[b][r] = zg[r]; }
        }
        __syncthreads();
        float seqv0 = seq[((size_t)(brow + wave) * T_ + 0) * FS_ + lane];
        float seqv1 = seq[((size_t)(brow + wave + 8) * T_ + 0) * FS_ + lane];

#pragma unroll 1
        for (int t = 0; t < T_; t++) {
            int p = t & 1;
            pinrec();
            // launder x0s so LICM can't ALSO pin these 8 frags (+32 VGPR > budget)
            const __hip_bfloat16* x0s = ws + WS_X0S;
            asm volatile("" : "+s"(x0s));

            xsb[wave][lane]     = __float2bfloat16(seqv0);
            xsb[wave + 8][lane] = __float2bfloat16(seqv1);
            if (tid == 0 && t >= 2) {   // slot p free? (B consumed t-2 -> ack = t-1)
                int guard = 1 << 27;
                while (__hip_atomic_load(&ackf[p], __ATOMIC_RELAXED,
                                         __HIP_MEMORY_SCOPE_AGENT) < t - 1 && --guard) {}
            }
            __syncthreads();
            {   // x0 projection + d0
                bfrag a0 = *(const bfrag*)&xsb[lm][qq * 8];
                bfrag a1 = *(const bfrag*)&xsb[lm][32 + qq * 8];
#pragma unroll
                for (int b = 0; b < 2; b++) {
                    int ct = 2 * wave + b;
                    bfrag w0 = *(const bfrag*)(x0s + ((4 * ct + 0) * 64 + lane) * 8);
                    bfrag w1 = *(const bfrag*)(x0s + ((4 * ct + 1) * 64 + lane) * 8);
                    bfrag g0 = *(const bfrag*)(x0s + ((4 * ct + 2) * 64 + lane) * 8);
                    bfrag g1 = *(const bfrag*)(x0s + ((4 * ct + 3) * 64 + lane) * 8);
                    ffrag zw, zg;
#pragma unroll
                    for (int r = 0; r < 4; r++) { zw[r] = xcw[b][r]; zg[r] = xcg[b][r] + bgr[b]; }
                    zw = mfma16(a0, w0, zw); zw = mfma16(a1, w1, zw);
                    zg = mfma16(a0, g0, zg); zg = mfma16(a1, g1, zg);
#pragma unroll
                    for (int r = 0; r < 4; r++) { xwin[b][r] = zw[r]; xgate[b][r] = zg[r]; }
                }
                loadbase();
                int tn = (t + 1 < T_) ? t + 1 : t;
                seqv0 = seq[((size_t)(brow + wave) * T_ + tn) * FS_ + lane];
                seqv1 = seq[((size_t)(brow + wave + 8) * T_ + tn) * FS_ + lane];
                deriv(abf[0], abf[1], 0);
            }
            bar_lds(); deriv(abf[1], abf[0], 1);
            bar_lds(); deriv(abf[0], abf[1], 2);
            bar_lds(); deriv(abf[1], abf[0], 3);
            bar_lds();
            lnorm(mb0 + p * 4096);
            asm volatile("s_waitcnt vmcnt(0)" ::: "memory");   // drain sc1 stores
            __syncthreads();
            if (tid == 0)
                __hip_atomic_store(&pubf[p], t + 1, __ATOMIC_RELEASE,
                                   __HIP_MEMORY_SCOPE_AGENT);
        }
        return;
    }

    // =================== role B: layer 1 consumer + head ===================
#pragma unroll 1
    for (int t = 0; t < T_; t++) {
        int p = t & 1;
        pinrec();
        const __hip_bfloat16* xp = ws + WS_X1P;
        asm volatile("" : "+s"(xp));    // block LICM pinning of streamed x1p frags
        if (tid == 0) {   // wait for A's publish of step t
            int guard = 1 << 27;
            while (__hip_atomic_load(&pubf[p], __ATOMIC_RELAXED,
                                     __HIP_MEMORY_SCOPE_AGENT) < t + 1 && --guard) {}
        }
        __syncthreads();
        {   // stage mailbox -> LDS (512 thr x 16 B, sc1 bypass loads: always fresh)
            int r = tid >> 5, c0 = (tid & 31) * 8;
            unsigned long long v0 = __hip_atomic_load(
                (const unsigned long long*)&mb0[p * 4096 + r * 256 + c0],
                __ATOMIC_RELAXED, __HIP_MEMORY_SCOPE_AGENT);
            unsigned long long v1 = __hip_atomic_load(
                (const unsigned long long*)&mb0[p * 4096 + r * 256 + c0 + 4],
                __ATOMIC_RELAXED, __HIP_MEMORY_SCOPE_AGENT);
            *(unsigned long long*)&x1A[r][c0]     = v0;
            *(unsigned long long*)&x1A[r][c0 + 4] = v1;
        }
        __syncthreads();
        if (tid == 0)
            __hip_atomic_store(&ackf[p], t + 1, __ATOMIC_RELEASE,
                               __HIP_MEMORY_SCOPE_AGENT);
        {   // x1 projection: A = h0(t) from LDS, B streamed from L2 (half-batches)
            ffrag zw[2], zg[2];
#pragma unroll
            for (int b = 0; b < 2; b++) {
                zw[b] = (ffrag){0.f, 0.f, 0.f, 0.f};
#pragma unroll
                for (int r = 0; r < 4; r++) zg[b][r] = bgr[b];
            }
#pragma unroll
            for (int b = 0; b < 2; b++) {
                int ct = 2 * wave + b;
#pragma unroll
                for (int half = 0; half < 2; half++) {
                    bfrag wv[4], gv[4];
#pragma unroll
                    for (int j = 0; j < 4; j++) {
                        int ks = half * 4 + j;
                        wv[j] = *(const bfrag*)(xp + ((16 * ct + ks) * 64 + lane) * 8);
                        gv[j] = *(const bfrag*)(xp + ((16 * ct + 8 + ks) * 64 + lane) * 8);
                    }
#pragma unroll
                    for (int j = 0; j < 4; j++) {
                        int ks = half * 4 + j;
                        bfrag a = *(const bfrag*)&x1A[lm][ks * 32 + qq * 8];
                        zw[b] = mfma16(a, wv[j], zw[b]);
                        zg[b] = mfma16(a, gv[j], zg[b]);
                    }
                }
            }
#pragma unroll
            for (int b = 0; b < 2; b++)
#pragma unroll
                for (int r = 0; r < 4; r++) { xwin[b][r] = zw[b][r]; xgate[b][r] = zg[b][r]; }
            loadbase();
            deriv(abf[0], abf[1], 0);
        }
        bar_lds(); deriv(abf[1], abf[0], 1);
        bar_lds(); deriv(abf[0], abf[1], 2);
        bar_lds(); deriv(abf[1], abf[0], 3);
        bar_lds();
        lnorm(nullptr);
        __syncthreads();
    }

    // ---- head: hid = relu(h1 @ cW1^T + cb1); out = hid @ cW2^T + cb2 ----
#pragma unroll
    for (int i = 0; i < 2; i++) {
        int rr = wave + i * 8;
        float acc0 = cb1[lane], acc1 = cb1[lane + 64];
        const float* w0 = cW1 + (size_t)lane * H_;
        const float* w1 = cW1 + (size_t)(lane + 64) * H_;
        for (int k = 0; k < H_; k += 4) {
            float4 hv = *(const float4*)&hbuf[rr][k];
            acc0 += hv.x * w0[k] + hv.y * w0[k+1] + hv.z * w0[k+2] + hv.w * w0[k+3];
            acc1 += hv.x * w1[k] + hv.y * w1[k+1] + hv.z * w1[k+2] + hv.w * w1[k+3];
        }
        __syncthreads();
        hn[rr][lane]      = fmaxf(acc0, 0.f);
        hn[rr][lane + 64] = fmaxf(acc1, 0.f);
    }
    __syncthreads();
    if (tid < 16) {
        float acc = cb2[0];
        for (int k = 0; k < 128; k++) acc += hn[tid][k] * cW2[k];
        out[brow + tid] = acc;
    }
}

extern "C" void kernel_launch(void* const* d_in, const int* in_sizes, int n_in,
                              void* d_out, int out_size, void* d_ws, size_t ws_size,
                              hipStream_t stream) {
    const float* seq   = (const float*)d_in[0];
    const float* ctx   = (const float*)d_in[1];
    const float* tau0  = (const float*)d_in[2];
    const float* Win0  = (const float*)d_in[3];
    const float* Wrec0 = (const float*)d_in[4];
    const float* Wg0   = (const float*)d_in[5];
    const float* bg0   = (const float*)d_in[6];
    const float* lng0  = (const float*)d_in[7];
    const float* lnb0  = (const float*)d_in[8];
    const float* tau1  = (const float*)d_in[9];
    const float* Win1  = (const float*)d_in[10];
    const float* Wrec1 = (const float*)d_in[11];
    const float* Wg1   = (const float*)d_in[12];
    const float* bg1   = (const float*)d_in[13];
    const float* lng1  = (const float*)d_in[14];
    const float* lnb1  = (const float*)d_in[15];
    const float* cW1   = (const float*)d_in[16];
    const float* cb1   = (const float*)d_in[17];
    const float* cW2   = (const float*)d_in[18];
    const float* cb2   = (const float*)d_in[19];
    __hip_bfloat16* ws = (__hip_bfloat16*)d_ws;

    hipLaunchKernelGGL(prepack_kernel, dim3(216), dim3(256), 0, stream,
                       Win0, Wrec0, Wg0, Win1, Wrec1, Wg1, ws);
    hipLaunchKernelGGL(lnn_main, dim3(64), dim3(512), 0, stream,
                       seq, ctx, tau0, bg0, lng0, lnb0, tau1, bg1, lng1, lnb1,
                       cW1, cb1, cW2, cb2, ws, (float*)d_out);
}

// Round 10
// 4052.962 us; speedup vs baseline: 1.1615x; 1.1615x over previous
//
#include <hip/hip_runtime.h>
#include <hip/hip_bf16.h>

#define T_  512
#define FS_ 64
#define FC_ 32
#define H_  256
#define APAD 272

// ws layout (bf16 element offsets)
#define WS_REC0 0        // [32 ft][8 ks][64 lane][8]   even ft = Wg_h, odd = Wrec
#define WS_REC1 131072
#define WS_X1P  262144   // [32][8][64][8]              even ft = Win1, odd = Wg_x1
#define WS_X0S  393216   // [32][2][64][8]              even ft = Win0, odd = Wg_x0
#define WS_X0C  425984   // [32][1][64][8]
#define WS_MBOX 458752   // [32 tiles][2 parity][16*256] bf16 h0 mailbox
#define WS_FLAG_BYTE ((458752 + 262144) * 2)   // 128 ints: pub[64], ack[64]

typedef __attribute__((ext_vector_type(8))) short bfrag;
typedef __attribute__((ext_vector_type(4))) float ffrag;

__device__ __forceinline__ ffrag mfma16(bfrag a, bfrag b, ffrag c) {
    return __builtin_amdgcn_mfma_f32_16x16x32_bf16(a, b, c, 0, 0, 0);
}
__device__ __forceinline__ float fast_tanh(float x) {
    float e = __builtin_amdgcn_exp2f(x * 2.8853901817f);   // exp(2x), inf-safe
    return 1.f - 2.f * __builtin_amdgcn_rcpf(e + 1.f);
}
__device__ __forceinline__ void bar_lds() {
    asm volatile("s_waitcnt lgkmcnt(0)\n\ts_barrier" ::: "memory");
}

// ---------------- prepack: fp32 weights -> bf16 MFMA B-fragments + flag reset ---
__global__ __launch_bounds__(256) void prepack_kernel(
    const float* __restrict__ Win0, const float* __restrict__ Wrec0, const float* __restrict__ Wg0,
    const float* __restrict__ Win1, const float* __restrict__ Wrec1, const float* __restrict__ Wg1,
    __hip_bfloat16* __restrict__ ws)
{
    int g = blockIdx.x * 256 + threadIdx.x;
    if (g < 128) ((int*)((char*)ws + WS_FLAG_BYTE))[g] = 0;   // pub/ack flags: reset every launch
    if (g >= 55296) return;
    int lane = g & 63;
    int frag = g >> 6;
    int lm = lane & 15, qq = lane >> 4;
    const float* src;
    int dstoff;
    if (frag < 256) {
        int f = frag, ft = f >> 3, ks = f & 7;
        int n = (ft >> 1) * 16 + lm, kk = ks * 32 + qq * 8;
        src = (ft & 1) ? (Wrec0 + n * 256 + kk) : (Wg0 + n * 352 + 96 + kk);
        dstoff = WS_REC0 + (f * 64 + lane) * 8;
    } else if (frag < 512) {
        int f = frag - 256, ft = f >> 3, ks = f & 7;
        int n = (ft >> 1) * 16 + lm, kk = ks * 32 + qq * 8;
        src = (ft & 1) ? (Wrec1 + n * 256 + kk) : (Wg1 + n * 512 + 256 + kk);
        dstoff = WS_REC1 + (f * 64 + lane) * 8;
    } else if (frag < 768) {
        int f = frag - 512, ft = f >> 3, ks = f & 7;
        int n = (ft >> 1) * 16 + lm, kk = ks * 32 + qq * 8;
        src = (ft & 1) ? (Wg1 + n * 512 + kk) : (Win1 + n * 256 + kk);
        dstoff = WS_X1P + (f * 64 + lane) * 8;
    } else if (frag < 832) {
        int f = frag - 768, ft = f >> 1, ks = f & 1;
        int n = (ft >> 1) * 16 + lm, kk = ks * 32 + qq * 8;
        src = (ft & 1) ? (Wg0 + n * 352 + kk) : (Win0 + n * 96 + kk);
        dstoff = WS_X0S + (f * 64 + lane) * 8;
    } else {
        int f = frag - 832, ft = f;
        int n = (ft >> 1) * 16 + lm, kk = qq * 8;
        src = (ft & 1) ? (Wg0 + n * 352 + 64 + kk) : (Win0 + n * 96 + 64 + kk);
        dstoff = WS_X0C + (f * 64 + lane) * 8;
    }
    __hip_bfloat16* d = ws + dstoff;
#pragma unroll
    for (int j = 0; j < 8; j++) d[j] = __float2bfloat16(src[j]);
}

// ---------------- main: 64 WGs = 32 layer-0 producers + 32 layer-1 consumers ----
// R8 topology (A/B pipelined via sc1 mailbox), re-geometried so the weight set
// FITS the 128-VGPR budget the allocator actually honors (R3/R8/R9 all chose
// 128; every coercion attempt failed): 16 waves x C=1 col-block per wave ->
// 16 frags = 64 VGPR of rec/gate weights + ~60 working regs < 128. LICM can now
// hoist the pre-loop weight loads and keep them RESIDENT, killing the per-deriv
// 256 KB/CU L2 restream (~7 us of R3/R8's 8.7 us step). LDS A-frag reads double
// (broadcast amortization lost) but cost only ~0.5 us/deriv. No asm pins (spill
// risk if estimate is off); waves_per_eu(4,4) removes the allocator's option of
// targeting 64 VGPR / 8 waves (R5's failure mode).
__global__ __attribute__((amdgpu_flat_work_group_size(1024, 1024),
                          amdgpu_waves_per_eu(4, 4))) void lnn_main(
    const float* __restrict__ seq, const float* __restrict__ ctx,
    const float* __restrict__ tau0, const float* __restrict__ bg0,
    const float* __restrict__ lng0, const float* __restrict__ lnb0,
    const float* __restrict__ tau1, const float* __restrict__ bg1,
    const float* __restrict__ lng1, const float* __restrict__ lnb1,
    const float* __restrict__ cW1, const float* __restrict__ cb1,
    const float* __restrict__ cW2, const float* __restrict__ cb2,
    __hip_bfloat16* __restrict__ ws, float* __restrict__ out)
{
    __shared__ __align__(16) float hbuf[16][260];
    __shared__ __align__(16) float hn[16][260];
    __shared__ __align__(16) __hip_bfloat16 abf[2][16][APAD];
    __shared__ __align__(16) __hip_bfloat16 x1A[16][APAD];     // B: staged h0 tile
    __shared__ __align__(16) __hip_bfloat16 xsb[16][80];       // A: ctx/seq staging
    __shared__ __align__(16) float lnw[256], lnb[256];

    const int tid  = threadIdx.x;
    const int wave = tid >> 6, lane = tid & 63;     // 16 waves
    const int qq   = lane >> 4, lm = lane & 15;
    const int bid  = blockIdx.x;
    const int tile = bid & 31, roleB = bid >> 5;
    const int brow = tile * 16;

    int* flags = (int*)((char*)ws + WS_FLAG_BYTE);
    int* pubf  = flags + tile * 2;          // [parity]
    int* ackf  = flags + 64 + tile * 2;     // [parity]
    __hip_bfloat16* mb0 = ws + WS_MBOX + tile * 2 * 4096;

    for (int e = tid; e < 16 * 260; e += 1024) ((float*)hbuf)[e] = 0.f;
    for (int e = tid; e < 2 * 16 * APAD; e += 1024)
        ((__hip_bfloat16*)abf)[e] = __float2bfloat16(0.f);
    if (tid < 256) {
        const float* lg = roleB ? lng1 : lng0;
        const float* lb = roleB ? lnb1 : lnb0;
        lnw[tid] = lg[tid]; lnb[tid] = lb[tid];
    }
    // per-wave column params: colb = wave*16 + lm  (C=1, ct = wave)
    float rtp, bgr;
    {
        int colb = wave * 16 + lm;
        float tv = roleB ? tau1[colb] : tau0[colb];
        float sp = fmaxf(tv, 0.f) + logf(1.f + __expf(-fabsf(tv)));
        rtp = 1.f / (sp + 1.f);
        bgr = roleB ? bg1[colb] : bg0[colb];
    }

    // ---- rec/gate weights: 1 col-block x 8 ks x (gate,rec) = 64 VGPR.
    // Loaded ONCE pre-loop; fits the 128 budget -> stays register-resident.
    bfrag cg[8], cr[8];
    {
        const __hip_bfloat16* rp = ws + (roleB ? WS_REC1 : WS_REC0);
#pragma unroll
        for (int ks = 0; ks < 8; ks++) {
            cg[ks] = *(const bfrag*)(rp + ((16 * wave + ks) * 64 + lane) * 8);
            cr[ks] = *(const bfrag*)(rp + ((16 * wave + 8 + ks) * 64 + lane) * 8);
        }
    }

    float xwin[4], xgate[4], hbase[4], hh[4], ksum[4];

    auto deriv = [&](const __hip_bfloat16 (*Ar)[APAD], __hip_bfloat16 (*Aw)[APAD], int d) {
        ffrag ag = {0.f, 0.f, 0.f, 0.f}, ar = {0.f, 0.f, 0.f, 0.f};
#pragma unroll
        for (int ks = 0; ks < 8; ks++) {
            bfrag a = *(const bfrag*)&Ar[lm][ks * 32 + qq * 8];
            ag = mfma16(a, cg[ks], ag);
            ar = mfma16(a, cr[ks], ar);
        }
        float wsm = (d == 1 || d == 2) ? 2.f : 1.f;
        float an  = (d < 2) ? 0.5f : 1.f;
        int colb = wave * 16 + lm;
#pragma unroll
        for (int r = 0; r < 4; r++) {
            float t  = fast_tanh(ag[r] + xgate[r]);
            float t2 = t * t;
            float g  = 0.5f + t * (0.25f + t2 * (-(1.f / 48.f) + t2 * (1.f / 480.f)));
            float kd = xwin[r] - hh[r] * rtp + g * ar[r];
            ksum[r] += wsm * kd;
            if (d < 3) {
                float hhn = hbase[r] + an * kd;
                hh[r] = hhn;
                Aw[qq * 4 + r][colb] = __float2bfloat16(hhn);
            } else {
                hn[qq * 4 + r][colb] = hbase[r] + ksum[r] * (1.f / 6.f);
            }
        }
    };
    auto loadbase = [&]() {
        int colb = wave * 16 + lm;
#pragma unroll
        for (int r = 0; r < 4; r++) {
            float v = hbuf[qq * 4 + r][colb];
            hbase[r] = v; hh[r] = v; ksum[r] = 0.f;
        }
    };
    auto lnorm = [&](__hip_bfloat16* mbslot) {
        // 16 waves x 1 row each
        int rr = wave, c0 = lane * 4;
        float4 vv = *(const float4*)&hn[rr][c0];
        float v[4] = {vv.x, vv.y, vv.z, vv.w};
        float s  = v[0] + v[1] + v[2] + v[3];
        float s2 = v[0]*v[0] + v[1]*v[1] + v[2]*v[2] + v[3]*v[3];
#pragma unroll
        for (int m = 1; m <= 32; m <<= 1) {
            s  += __shfl_xor(s, m, 64);
            s2 += __shfl_xor(s2, m, 64);
        }
        float mean = s * (1.f / 256.f);
        float var  = s2 * (1.f / 256.f) - mean * mean;
        float rs   = __builtin_amdgcn_rsqf(var + 1e-5f);
        float4 lw = *(const float4*)&lnw[c0];
        float4 lb = *(const float4*)&lnb[c0];
        float hv[4];
        __align__(8) __hip_bfloat16 hb[4];
        hv[0] = fast_tanh((v[0] - mean) * rs * lw.x + lb.x);
        hv[1] = fast_tanh((v[1] - mean) * rs * lw.y + lb.y);
        hv[2] = fast_tanh((v[2] - mean) * rs * lw.z + lb.z);
        hv[3] = fast_tanh((v[3] - mean) * rs * lw.w + lb.w);
#pragma unroll
        for (int j = 0; j < 4; j++) hb[j] = __float2bfloat16(hv[j]);
        *(float4*)&hbuf[rr][c0] = (float4){hv[0], hv[1], hv[2], hv[3]};
        *(uint2*)&abf[0][rr][c0] = *(uint2*)hb;
        if (mbslot)
            __hip_atomic_store((unsigned long long*)&mbslot[rr * 256 + c0],
                               *(unsigned long long*)hb,
                               __ATOMIC_RELAXED, __HIP_MEMORY_SCOPE_AGENT);
    };

    if (!roleB) {
        // =================== role A: layer 0 producer ===================
        for (int e = tid; e < 16 * FC_; e += 1024) {
            int r = e >> 5, c = e & 31;
            xsb[r][c] = __float2bfloat16(ctx[(brow + r) * FC_ + c]);
        }
        __syncthreads();
        float xcw[4], xcg[4];
        {
            bfrag a = *(const bfrag*)&xsb[lm][qq * 8];
            ffrag zw = {0.f, 0.f, 0.f, 0.f}, zg = {0.f, 0.f, 0.f, 0.f};
            bfrag bw  = *(const bfrag*)(ws + WS_X0C + ((2 * wave) * 64 + lane) * 8);
            bfrag bgf = *(const bfrag*)(ws + WS_X0C + ((2 * wave + 1) * 64 + lane) * 8);
            zw = mfma16(a, bw, zw);
            zg = mfma16(a, bgf, zg);
#pragma unroll
            for (int r = 0; r < 4; r++) { xcw[r] = zw[r]; xcg[r] = zg[r]; }
        }
        __syncthreads();
        float seqv = seq[((size_t)(brow + wave) * T_ + 0) * FS_ + lane];

#pragma unroll 1
        for (int t = 0; t < T_; t++) {
            int p = t & 1;
            // launder x0s so LICM can't ALSO pin these 4 frags (+16 VGPR > budget)
            const __hip_bfloat16* x0s = ws + WS_X0S;
            asm volatile("" : "+s"(x0s));

            xsb[wave][lane] = __float2bfloat16(seqv);
            if (tid == 0 && t >= 2) {   // slot p free? (B consumed t-2 -> ack = t-1)
                int guard = 1 << 27;
                while (__hip_atomic_load(&ackf[p], __ATOMIC_RELAXED,
                                         __HIP_MEMORY_SCOPE_AGENT) < t - 1 && --guard) {}
            }
            __syncthreads();
            {   // x0 projection + d0   (ct = wave)
                bfrag a0 = *(const bfrag*)&xsb[lm][qq * 8];
                bfrag a1 = *(const bfrag*)&xsb[lm][32 + qq * 8];
                bfrag w0 = *(const bfrag*)(x0s + ((4 * wave + 0) * 64 + lane) * 8);
                bfrag w1 = *(const bfrag*)(x0s + ((4 * wave + 1) * 64 + lane) * 8);
                bfrag g0 = *(const bfrag*)(x0s + ((4 * wave + 2) * 64 + lane) * 8);
                bfrag g1 = *(const bfrag*)(x0s + ((4 * wave + 3) * 64 + lane) * 8);
                ffrag zw, zg;
#pragma unroll
                for (int r = 0; r < 4; r++) { zw[r] = xcw[r]; zg[r] = xcg[r] + bgr; }
                zw = mfma16(a0, w0, zw); zw = mfma16(a1, w1, zw);
                zg = mfma16(a0, g0, zg); zg = mfma16(a1, g1, zg);
#pragma unroll
                for (int r = 0; r < 4; r++) { xwin[r] = zw[r]; xgate[r] = zg[r]; }
                loadbase();
                int tn = (t + 1 < T_) ? t + 1 : t;
                seqv = seq[((size_t)(brow + wave) * T_ + tn) * FS_ + lane];
                deriv(abf[0], abf[1], 0);
            }
            bar_lds(); deriv(abf[1], abf[0], 1);
            bar_lds(); deriv(abf[0], abf[1], 2);
            bar_lds(); deriv(abf[1], abf[0], 3);
            bar_lds();
            lnorm(mb0 + p * 4096);
            asm volatile("s_waitcnt vmcnt(0)" ::: "memory");   // drain sc1 stores
            __syncthreads();
            if (tid == 0)
                __hip_atomic_store(&pubf[p], t + 1, __ATOMIC_RELEASE,
                                   __HIP_MEMORY_SCOPE_AGENT);
        }
        return;
    }

    // =================== role B: layer 1 consumer + head ===================
#pragma unroll 1
    for (int t = 0; t < T_; t++) {
        int p = t & 1;
        const __hip_bfloat16* xp = ws + WS_X1P;
        asm volatile("" : "+s"(xp));    // block LICM pinning of streamed x1p frags
        if (tid == 0) {   // wait for A's publish of step t
            int guard = 1 << 27;
            while (__hip_atomic_load(&pubf[p], __ATOMIC_RELAXED,
                                     __HIP_MEMORY_SCOPE_AGENT) < t + 1 && --guard) {}
        }
        __syncthreads();
        {   // stage mailbox -> LDS (1024 thr x 8 B, sc1 bypass loads: always fresh)
            int r = tid >> 6, c0 = (tid & 63) * 4;
            unsigned long long v = __hip_atomic_load(
                (const unsigned long long*)&mb0[p * 4096 + r * 256 + c0],
                __ATOMIC_RELAXED, __HIP_MEMORY_SCOPE_AGENT);
            *(unsigned long long*)&x1A[r][c0] = v;
        }
        __syncthreads();
        if (tid == 0)
            __hip_atomic_store(&ackf[p], t + 1, __ATOMIC_RELEASE,
                               __HIP_MEMORY_SCOPE_AGENT);
        {   // x1 projection: A = h0(t) from LDS, B streamed from L2 (half-batches)
            ffrag zw = {0.f, 0.f, 0.f, 0.f}, zg;
#pragma unroll
            for (int r = 0; r < 4; r++) zg[r] = bgr;
#pragma unroll
            for (int half = 0; half < 2; half++) {
                bfrag wv[4], gv[4];
#pragma unroll
                for (int j = 0; j < 4; j++) {
                    int ks = half * 4 + j;
                    wv[j] = *(const bfrag*)(xp + ((16 * wave + ks) * 64 + lane) * 8);
                    gv[j] = *(const bfrag*)(xp + ((16 * wave + 8 + ks) * 64 + lane) * 8);
                }
#pragma unroll
                for (int j = 0; j < 4; j++) {
                    int ks = half * 4 + j;
                    bfrag a = *(const bfrag*)&x1A[lm][ks * 32 + qq * 8];
                    zw = mfma16(a, wv[j], zw);
                    zg = mfma16(a, gv[j], zg);
                }
            }
#pragma unroll
            for (int r = 0; r < 4; r++) { xwin[r] = zw[r]; xgate[r] = zg[r]; }
            loadbase();
            deriv(abf[0], abf[1], 0);
        }
        bar_lds(); deriv(abf[1], abf[0], 1);
        bar_lds(); deriv(abf[0], abf[1], 2);
        bar_lds(); deriv(abf[1], abf[0], 3);
        bar_lds();
        lnorm(nullptr);
        __syncthreads();
    }

    // ---- head: hid = relu(h1 @ cW1^T + cb1); out = hid @ cW2^T + cb2 ----
    {
        int rr = wave;   // 16 waves, one row each
        float acc0 = cb1[lane], acc1 = cb1[lane + 64];
        const float* w0 = cW1 + (size_t)lane * H_;
        const float* w1 = cW1 + (size_t)(lane + 64) * H_;
        for (int k = 0; k < H_; k += 4) {
            float4 hv = *(const float4*)&hbuf[rr][k];
            acc0 += hv.x * w0[k] + hv.y * w0[k+1] + hv.z * w0[k+2] + hv.w * w0[k+3];
            acc1 += hv.x * w1[k] + hv.y * w1[k+1] + hv.z * w1[k+2] + hv.w * w1[k+3];
        }
        __syncthreads();
        hn[rr][lane]      = fmaxf(acc0, 0.f);
        hn[rr][lane + 64] = fmaxf(acc1, 0.f);
    }
    __syncthreads();
    if (tid < 16) {
        float acc = cb2[0];
        for (int k = 0; k < 128; k++) acc += hn[tid][k] * cW2[k];
        out[brow + tid] = acc;
    }
}

extern "C" void kernel_launch(void* const* d_in, const int* in_sizes, int n_in,
                              void* d_out, int out_size, void* d_ws, size_t ws_size,
                              hipStream_t stream) {
    const float* seq   = (const float*)d_in[0];
    const float* ctx   = (const float*)d_in[1];
    const float* tau0  = (const float*)d_in[2];
    const float* Win0  = (const float*)d_in[3];
    const float* Wrec0 = (const float*)d_in[4];
    const float* Wg0   = (const float*)d_in[5];
    const float* bg0   = (const float*)d_in[6];
    const float* lng0  = (const float*)d_in[7];
    const float* lnb0  = (const float*)d_in[8];
    const float* tau1  = (const float*)d_in[9];
    const float* Win1  = (const float*)d_in[10];
    const float* Wrec1 = (const float*)d_in[11];
    const float* Wg1   = (const float*)d_in[12];
    const float* bg1   = (const float*)d_in[13];
    const float* lng1  = (const float*)d_in[14];
    const float* lnb1  = (const float*)d_in[15];
    const float* cW1   = (const float*)d_in[16];
    const float* cb1   = (const float*)d_in[17];
    const float* cW2   = (const float*)d_in[18];
    const float* cb2   = (const float*)d_in[19];
    __hip_bfloat16* ws = (__hip_bfloat16*)d_ws;

    hipLaunchKernelGGL(prepack_kernel, dim3(216), dim3(256), 0, stream,
                       Win0, Wrec0, Wg0, Win1, Wrec1, Wg1, ws);
    hipLaunchKernelGGL(lnn_main, dim3(64), dim3(1024), 0, stream,
                       seq, ctx, tau0, bg0, lng0, lnb0, tau1, bg1, lng1, lnb1,
                       cW1, cb1, cW2, cb2, ws, (float*)d_out);
}